// Round 1
// baseline (311.577 us; speedup 1.0000x reference)
//
#include <hip/hip_runtime.h>

#define INV_SQRT2 0.70710678118654752f
#define QSCALE    0.17677669529663689f   // 1/sqrt(HEAD_DIM=32)

typedef __attribute__((ext_vector_type(8))) short bf16x8;
typedef __attribute__((ext_vector_type(4))) float f32x4;

__device__ __forceinline__ short f2bf(float x) {
  union { float f; unsigned int u; } v; v.f = x;
  unsigned int r = v.u + 0x7FFFu + ((v.u >> 16) & 1u);  // RNE
  return (short)(r >> 16);
}

// ---- DWT for q,k: (B,S,512)f32 -> (16,S,256)bf16, scale folded into q ----
__global__ void dwt_qk(const float* __restrict__ q, const float* __restrict__ k,
                       short* __restrict__ qs, short* __restrict__ ks) {
  int idx = blockIdx.x * 256 + threadIdx.x;   // (b*2048+s)*256 + i
  int b = idx >> 19;
  int si = idx & 0x7FFFF;
  float2 qv = ((const float2*)q)[idx];
  float2 kv = ((const float2*)k)[idx];
  size_t base_l = ((size_t)(b * 2) << 19) + si;
  size_t base_h = base_l + (1u << 19);
  qs[base_l] = f2bf((qv.x + qv.y) * (INV_SQRT2 * QSCALE));
  qs[base_h] = f2bf((qv.x - qv.y) * (INV_SQRT2 * QSCALE));
  ks[base_l] = f2bf((kv.x + kv.y) * INV_SQRT2);
  ks[base_h] = f2bf((kv.x - kv.y) * INV_SQRT2);
}

// ---- DWT for v + transpose: (B,S,512)f32 -> vt (16,256,2048)bf16 ----
__global__ void dwt_v(const float* __restrict__ v, short* __restrict__ vt) {
  __shared__ float tL[64][65];
  __shared__ float tH[64][65];
  int t = threadIdx.x;
  int it = blockIdx.x, st = blockIdx.y, b = blockIdx.z;
#pragma unroll
  for (int rep = 0; rep < 16; rep++) {
    int item = rep * 256 + t;
    int r = item >> 6, c = item & 63;
    float2 vv = ((const float2*)v)[((size_t)(b * 2048 + st * 64 + r)) * 256 + it * 64 + c];
    tL[r][c] = (vv.x + vv.y) * INV_SQRT2;
    tH[r][c] = (vv.x - vv.y) * INV_SQRT2;
  }
  __syncthreads();
#pragma unroll
  for (int rep = 0; rep < 16; rep++) {
    int item = rep * 256 + t;
    int i = item >> 6, sc = item & 63;
    size_t o = ((size_t)((b * 2) * 256 + it * 64 + i)) * 2048 + st * 64 + sc;
    vt[o] = f2bf(tL[sc][i]);
    vt[o + 256 * 2048] = f2bf(tH[sc][i]);
  }
}

// ---- fuse iDWT into W_o:  w2[j][i]=(W[j][2i]+W[j][2i+1])/sqrt2 ; w2[j][256+i]=diff ----
__global__ void w2k(const float* __restrict__ W, short* __restrict__ w2) {
  int idx = blockIdx.x * 256 + threadIdx.x;  // j*256 + i
  int j = idx >> 8, i = idx & 255;
  float a = W[j * 512 + 2 * i], c = W[j * 512 + 2 * i + 1];
  w2[j * 512 + i]       = f2bf((a + c) * INV_SQRT2);
  w2[j * 512 + 256 + i] = f2bf((a - c) * INV_SQRT2);
}

// ---- flash attention, 16 problems (b x branch), d=256, S=2048 ----
// block: 256 thr = 4 waves, BM=64 (16 q-rows/wave), BN=64, LDS = exactly 64KB:
//   [0,16384): K tile 64x256 bf16 (xor-swizzled chunks); P aliases first 4096 after S-read barrier
//   [16384,32768): V^T tile 256x64 bf16 (xor-swizzled)
__launch_bounds__(256, 2)
__global__ void flash_attn(const short* __restrict__ qs, const short* __restrict__ ks,
                           const short* __restrict__ vt, short* __restrict__ os) {
  __shared__ short lds[32768];
  short* klds = lds;
  short* vlds = lds + 16384;

  int tid = threadIdx.x;
  int w = tid >> 6;
  int L = tid & 63;
  int lo = L & 15, hi = L >> 4;
  int qb = blockIdx.x, bb = blockIdx.y;

  // Q fragments (A layout: m=lo, k = kc*32 + hi*8 + j), scale pre-folded
  bf16x8 qf[8];
  const short* qptr = qs + (((size_t)bb * 2048) + qb * 64 + w * 16 + lo) * 256;
#pragma unroll
  for (int kc = 0; kc < 8; kc++)
    qf[kc] = *(const bf16x8*)(qptr + kc * 32 + hi * 8);

  f32x4 oacc[16];
#pragma unroll
  for (int i = 0; i < 16; i++) oacc[i] = (f32x4){0.f, 0.f, 0.f, 0.f};
  float m_i[4], l_i[4];
#pragma unroll
  for (int r = 0; r < 4; r++) { m_i[r] = -1e30f; l_i[r] = 0.f; }

  const short* kbase = ks + ((size_t)bb * 2048) * 256;
  const short* vbase = vt + ((size_t)bb * 256) * 2048;

  for (int kt = 0; kt < 32; kt++) {
    __syncthreads();   // prior-iter P/V^T reads done before restage
    // stage K tile (64 rows x 32 chunks of 8 bf16, chunk c stored at c^(row&7))
#pragma unroll
    for (int rep = 0; rep < 8; rep++) {
      int cid = rep * 256 + tid;
      int row = cid >> 5, c = cid & 31;
      int c2 = c ^ (row & 7);
      *(bf16x8*)(klds + row * 256 + c2 * 8) =
          *(const bf16x8*)(kbase + ((size_t)(kt * 64 + row)) * 256 + c * 8);
    }
    // stage V^T tile (256 rows x 8 chunks)
#pragma unroll
    for (int rep = 0; rep < 8; rep++) {
      int cid = rep * 256 + tid;
      int n = cid >> 3, c = cid & 7;
      int c2 = c ^ (n & 7);
      *(bf16x8*)(vlds + n * 64 + c2 * 8) =
          *(const bf16x8*)(vbase + (size_t)n * 2048 + kt * 64 + c * 8);
    }
    __syncthreads();

    // S = Q K^T (4 col-tiles x 8 k-chunks)
    f32x4 sa[4];
#pragma unroll
    for (int ct = 0; ct < 4; ct++) sa[ct] = (f32x4){0.f, 0.f, 0.f, 0.f};
#pragma unroll
    for (int kc = 0; kc < 8; kc++) {
#pragma unroll
      for (int ct = 0; ct < 4; ct++) {
        bf16x8 kb = *(const bf16x8*)(klds + (ct * 16 + lo) * 256 +
                                     ((kc * 4 + hi) ^ (lo & 7)) * 8);
        sa[ct] = __builtin_amdgcn_mfma_f32_16x16x32_bf16(qf[kc], kb, sa[ct], 0, 0, 0);
      }
    }

    // online softmax: rows = hi*4+r, cols spread over lo and ct
    float vmax[4], rs[4], al[4];
#pragma unroll
    for (int r = 0; r < 4; r++)
      vmax[r] = fmaxf(fmaxf(sa[0][r], sa[1][r]), fmaxf(sa[2][r], sa[3][r]));
#pragma unroll
    for (int mask = 1; mask < 16; mask <<= 1)
#pragma unroll
      for (int r = 0; r < 4; r++)
        vmax[r] = fmaxf(vmax[r], __shfl_xor(vmax[r], mask, 64));
#pragma unroll
    for (int r = 0; r < 4; r++) {
      float mn = fmaxf(m_i[r], vmax[r]);
      al[r] = __expf(m_i[r] - mn);
      m_i[r] = mn;
    }
#pragma unroll
    for (int ct = 0; ct < 4; ct++)
#pragma unroll
      for (int r = 0; r < 4; r++)
        sa[ct][r] = __expf(sa[ct][r] - m_i[r]);
#pragma unroll
    for (int r = 0; r < 4; r++)
      rs[r] = (sa[0][r] + sa[1][r]) + (sa[2][r] + sa[3][r]);
#pragma unroll
    for (int mask = 1; mask < 16; mask <<= 1)
#pragma unroll
      for (int r = 0; r < 4; r++)
        rs[r] += __shfl_xor(rs[r], mask, 64);
#pragma unroll
    for (int r = 0; r < 4; r++)
      l_i[r] = l_i[r] * al[r] + rs[r];
#pragma unroll
    for (int nt = 0; nt < 16; nt++)
#pragma unroll
      for (int r = 0; r < 4; r++)
        oacc[nt][r] *= al[r];

    __syncthreads();   // all waves done reading K region before P overwrites it
    // write P bf16 into this wave's 16x64 slice (swizzled for A-frag reads)
    short* plds = klds + w * 1024;
#pragma unroll
    for (int ct = 0; ct < 4; ct++)
#pragma unroll
      for (int r = 0; r < 4; r++) {
        int mloc = hi * 4 + r;
        int col = ct * 16 + lo;
        int c2 = (col >> 3) ^ (mloc & 7);
        plds[mloc * 64 + c2 * 8 + (col & 7)] = f2bf(sa[ct][r]);
      }
    __syncthreads();

    // O += P V  (A=P 16x64, B=V^T frags)
    bf16x8 pf[2];
#pragma unroll
    for (int kc = 0; kc < 2; kc++)
      pf[kc] = *(const bf16x8*)(plds + lo * 64 + ((kc * 4 + hi) ^ (lo & 7)) * 8);
#pragma unroll
    for (int nt = 0; nt < 16; nt++)
#pragma unroll
      for (int kc = 0; kc < 2; kc++) {
        bf16x8 vb = *(const bf16x8*)(vlds + (nt * 16 + lo) * 64 +
                                     ((kc * 4 + hi) ^ (lo & 7)) * 8);
        oacc[nt] = __builtin_amdgcn_mfma_f32_16x16x32_bf16(pf[kc], vb, oacc[nt], 0, 0, 0);
      }
  }

  // epilogue: normalize, stage through LDS for coalesced bf16 stores
  __syncthreads();
#pragma unroll
  for (int nt = 0; nt < 16; nt++)
#pragma unroll
    for (int r = 0; r < 4; r++)
      lds[(w * 16 + hi * 4 + r) * 256 + nt * 16 + lo] = f2bf(oacc[nt][r] / l_i[r]);
  __syncthreads();
  short* obase = os + (((size_t)bb * 2048) + qb * 64) * 256;
#pragma unroll
  for (int rep = 0; rep < 8; rep++) {
    int cid = rep * 256 + tid;
    int row = cid >> 5, c = cid & 31;
    *(bf16x8*)(obase + row * 256 + c * 8) = *(const bf16x8*)(lds + row * 256 + c * 8);
  }
}

// ---- out = [O_L|O_H] @ w2^T + b_o : M=16384 N=512 K=512, 128x128 tiles ----
__launch_bounds__(256, 2)
__global__ void out_gemm(const short* __restrict__ os, const short* __restrict__ w2,
                         const float* __restrict__ bo, float* __restrict__ out) {
  __shared__ short alds[128 * 40];
  __shared__ short blds[128 * 40];
  int tid = threadIdx.x;
  int w = tid >> 6, L = tid & 63, lo = L & 15, hi = L >> 4;
  int wr = w >> 1, wc = w & 1;
  int br = blockIdx.x, bc = blockIdx.y;

  f32x4 acc[4][4];
#pragma unroll
  for (int mt = 0; mt < 4; mt++)
#pragma unroll
    for (int nt = 0; nt < 4; nt++)
      acc[mt][nt] = (f32x4){0.f, 0.f, 0.f, 0.f};

  for (int kt = 0; kt < 16; kt++) {
    __syncthreads();
#pragma unroll
    for (int rep = 0; rep < 2; rep++) {
      int cid = rep * 256 + tid;
      int mrow = cid >> 2, c = cid & 3;
      int gr = br * 128 + mrow;
      int b = gr >> 11, s = gr & 2047;
      int k = kt * 32 + c * 8;
      const short* src = os + ((size_t)((b * 2 + (k >> 8)) * 2048 + s)) * 256 + (k & 255);
      *(bf16x8*)(alds + mrow * 40 + c * 8) = *(const bf16x8*)src;
    }
#pragma unroll
    for (int rep = 0; rep < 2; rep++) {
      int cid = rep * 256 + tid;
      int nrow = cid >> 2, c = cid & 3;
      *(bf16x8*)(blds + nrow * 40 + c * 8) =
          *(const bf16x8*)(w2 + (size_t)(bc * 128 + nrow) * 512 + kt * 32 + c * 8);
    }
    __syncthreads();
    bf16x8 af[4], bfr[4];
#pragma unroll
    for (int mt = 0; mt < 4; mt++)
      af[mt] = *(const bf16x8*)(alds + (wr * 64 + mt * 16 + lo) * 40 + hi * 8);
#pragma unroll
    for (int nt = 0; nt < 4; nt++)
      bfr[nt] = *(const bf16x8*)(blds + (wc * 64 + nt * 16 + lo) * 40 + hi * 8);
#pragma unroll
    for (int mt = 0; mt < 4; mt++)
#pragma unroll
      for (int nt = 0; nt < 4; nt++)
        acc[mt][nt] = __builtin_amdgcn_mfma_f32_16x16x32_bf16(af[mt], bfr[nt], acc[mt][nt], 0, 0, 0);
  }

#pragma unroll
  for (int nt = 0; nt < 4; nt++) {
    int cc = bc * 128 + wc * 64 + nt * 16 + lo;
    float bias = bo[cc];
#pragma unroll
    for (int mt = 0; mt < 4; mt++) {
      int rrbase = br * 128 + wr * 64 + mt * 16 + hi * 4;
#pragma unroll
      for (int r = 0; r < 4; r++)
        out[(size_t)(rrbase + r) * 512 + cc] = acc[mt][nt][r] + bias;
    }
  }
}

extern "C" void kernel_launch(void* const* d_in, const int* in_sizes, int n_in,
                              void* d_out, int out_size, void* d_ws, size_t ws_size,
                              hipStream_t stream) {
  const float* q  = (const float*)d_in[0];
  const float* k  = (const float*)d_in[1];
  const float* v  = (const float*)d_in[2];
  const float* W  = (const float*)d_in[3];
  const float* bo = (const float*)d_in[4];
  short* ws  = (short*)d_ws;
  // each bf16 tensor (16,2048,256) = 8M elements
  short* qs  = ws;
  short* ksb = ws + (size_t)8  * 1024 * 1024;
  short* vtp = ws + (size_t)16 * 1024 * 1024;
  short* osb = ws + (size_t)24 * 1024 * 1024;
  short* w2  = ws + (size_t)32 * 1024 * 1024;   // 512x512
  // total ws use: 33,816,576 bf16 = ~64.5 MB

  dwt_qk<<<16384, 256, 0, stream>>>(q, k, qs, ksb);
  dwt_v<<<dim3(4, 32, 8), 256, 0, stream>>>(v, vtp);
  w2k<<<512, 256, 0, stream>>>(W, w2);
  flash_attn<<<dim3(32, 16), 256, 0, stream>>>(qs, ksb, vtp, osb);
  out_gemm<<<dim3(128, 4), 256, 0, stream>>>(osb, w2, bo, (float*)d_out);
}